// Round 1
// baseline (138.673 us; speedup 1.0000x reference)
//
#include <hip/hip_runtime.h>

#define NB    2000
#define NT    365
#define NMUL  8
#define LENF  15
#define PSTRIDE 96   // 12 params * 8 muls, floats per (b,t)

// One thread per (basin, mul). Block = 64 threads = 1 wave = 8 basins.
// Sequential 365-step scan with chunk-of-4 register prefetch pipeline;
// Q history staged in LDS; gamma-routing conv fused at the end
// (the exp(gammaln(aa))*th^aa denominator cancels under normalization).
__global__ __launch_bounds__(64) void prms_kernel(
    const float* __restrict__ P, const float* __restrict__ Ep,
    const float* __restrict__ Tair, const float* __restrict__ params,
    const float* __restrict__ rout_a, const float* __restrict__ rout_b,
    float* __restrict__ out)
{
  __shared__ float Qs[8][NT];

  const int tid = blockIdx.x * 64 + threadIdx.x;
  const int b   = tid >> 3;          // basin (grid sized exactly: no OOB)
  const int m   = tid & 7;           // mul index
  const int lb  = threadIdx.x >> 3;  // local basin 0..7

  const float* __restrict__ prm = params + (size_t)b * NT * PSTRIDE + m;
  const float* __restrict__ Pp  = P    + (size_t)b * NT;
  const float* __restrict__ Epp = Ep   + (size_t)b * NT;
  const float* __restrict__ Tp  = Tair + (size_t)b * NT;

  float S1 = 0.5f, S2 = 0.5f, S3 = 0.5f, S4 = 0.5f, S5 = 0.5f;

  // register pipeline buffers — indexed only by fully-unrolled constants
  float cur[4][12], nxt[4][12];

  auto LOAD = [&](int t, float* d) {
    const int tl = (t < NT) ? t : (NT - 1);   // clamp (harmless duplicate load)
    const float* q = prm + (size_t)tl * PSTRIDE;
    d[0] = q[0];   // pr0  tt
    d[1] = q[8];   // pr1  ddf
    d[2] = q[24];  // pr3  Smax3
    d[3] = q[32];  // pr4  p_lo
    d[4] = q[40];  // pr5  p_hi
    d[5] = q[48];  // pr6  p_exp
    d[6] = q[64];  // pr8  i1
    d[7] = q[72];  // pr9  i2
    d[8] = q[80];  // pr10 kb
    d[9]  = Pp[tl];
    d[10] = Epp[tl];
    d[11] = Tp[tl];
  };

  auto STEP = [&](const float* d, int t) {
    const float tt    = fmaf(d[0], 8.0f, -3.0f);
    const float ddf   = d[1] * 20.0f;
    const float Smax3 = fmaf(d[2], 680.0f, 20.0f);
    const float p_lo  = fmaf(d[3], 0.99f, 0.005f);
    const float p_hi  = fmaf(d[4], 0.99f, 0.005f);
    const float p_exp = fmaf(d[5], 4.0f, 1.0f);
    const float i1 = d[6];
    const float i2 = d[7] * 0.001f;
    const float kb = d[8];
    const float Pt = d[9], Ept = d[10], Tt = d[11];

    const float snow = (Tt <= tt) ? Pt : 0.0f;
    const float rain = Pt - snow;
    const float melt = fmaxf(fminf(ddf * (Tt - tt), S1), 0.0f);  // DT=1
    S1 = S1 + snow - melt;

    const float inter = rain * 0.95f;
    const float evap2 = fminf(S2, Ept);
    S2 = fmaxf(S2 + (rain - inter) - evap2, 0.0f);

    const float infil = melt + inter;
    const float frac  = fmaxf(S3, 0.0f) / Smax3;
    const float satexc = (p_lo + (p_hi - p_lo) * frac) * infil;
    const float rem  = fmaxf(infil - satexc, 0.0f);
    // frac^p_exp ; frac==0 -> log2=-inf -> exp2(-inf)=0  (matches 0**p, p>=1)
    const float rech = rem * exp2f(p_exp * log2f(frac));
    const float evap3 = fminf(frac * Ept, S3);
    S3 = S3 + rem - rech - evap3;

    const float S4c = fmaxf(S4, 0.0f);
    const float iflow = fminf(S4c, i1 * S4c + i2 * S4c * S4c);
    S4 = S4 + rech - iflow;

    const float base = kb * S5;
    S5 = S5 + iflow - base;

    float q = satexc + base;
    // mean over the 8 muls (lanes m=0..7 of this basin's lane-group)
    q += __shfl_xor(q, 1);
    q += __shfl_xor(q, 2);
    q += __shfl_xor(q, 4);
    if (m == 0) Qs[lb][t] = q * 0.125f;
  };

  // prologue: load chunk 0
  #pragma unroll
  for (int s = 0; s < 4; ++s) LOAD(s, cur[s]);

  // main pipeline: 91 chunks of 4 steps (t = 0..363)
  for (int t0 = 0; t0 < NT - 1; t0 += 4) {
    #pragma unroll
    for (int s = 0; s < 4; ++s) LOAD(t0 + 4 + s, nxt[s]);   // prefetch next chunk
    #pragma unroll
    for (int s = 0; s < 4; ++s) STEP(cur[s], t0 + s);       // compute current
    #pragma unroll
    for (int s = 0; s < 4; ++s) {
      #pragma unroll
      for (int j = 0; j < 12; ++j) cur[s][j] = nxt[s][j];
    }
  }
  // tail step t = 364 (loaded in the last prefetch)
  STEP(cur[0], NT - 1);

  __syncthreads();

  // ---- fused gamma routing conv ----
  // w[j] ∝ t_j^(aa-1) * exp(-t_j/th); the gammaln/th^aa denominator cancels
  // under w /= sum(w).
  const float aa  = fmaxf(rout_a[b] * 2.9f, 0.0f) + 0.1f;
  const float th  = fmaxf(rout_b[b] * 6.5f, 0.0f) + 0.5f;
  const float am1 = aa - 1.0f;
  const float ith = -1.0f / th;

  float w[LENF];
  float wsum = 0.0f;
  #pragma unroll
  for (int j = 0; j < LENF; ++j) {
    const float tj = (float)j + 0.5f;
    w[j] = exp2f(am1 * log2f(tj)) * expf(tj * ith);
    wsum += w[j];
  }
  const float inv = 1.0f / wsum;
  #pragma unroll
  for (int j = 0; j < LENF; ++j) w[j] *= inv;

  float* __restrict__ ob = out + (size_t)b * NT;
  for (int t = m; t < NT; t += NMUL) {
    float acc = 0.0f;
    #pragma unroll
    for (int j = 0; j < LENF; ++j) {
      const int idx = t - j;
      if (idx >= 0) acc += w[j] * Qs[lb][idx];
    }
    ob[t] = acc;
  }
}

extern "C" void kernel_launch(void* const* d_in, const int* in_sizes, int n_in,
                              void* d_out, int out_size, void* d_ws, size_t ws_size,
                              hipStream_t stream) {
  const float* P      = (const float*)d_in[0];
  const float* Ep     = (const float*)d_in[1];
  const float* Tair   = (const float*)d_in[2];
  const float* params = (const float*)d_in[3];
  const float* ra     = (const float*)d_in[4];
  const float* rb     = (const float*)d_in[5];
  float* out = (float*)d_out;

  prms_kernel<<<(NB * NMUL) / 64, 64, 0, stream>>>(P, Ep, Tair, params, ra, rb, out);
}